// Round 16
// baseline (114.239 us; speedup 1.0000x reference)
//
#include <hip/hip_runtime.h>
#include <math.h>

// Problem constants (match reference)
#define NROWS   8192
#define DDIM    1024
#define NSTEPS  50
#define NPAIR   8           // float2 pairs per lane (16 elements)
#define WPB     4           // waves per block -> 256 threads

// Adam hyperparams (double for host-side table computation)
#define LR_D   0.01
#define B1_D   0.9
#define B2_D   0.999
#define EPS_D  1e-8

typedef __attribute__((ext_vector_type(2))) float f32x2;

struct StepTbl {
    float alpha[NSTEPS];   // LR*(1-B1)*sqrt((1-B2^t)/(1-B2))/(1-B1^t)
    float delta[NSTEPS];   // eps2^2, eps2 = EPS*sqrt((1-B2^t)/(1-B2))
};

// DPP-permuted copy of v (f32 through int bit_cast). bound_ctrl=1 (0 on invalid).
template <int CTRL>
__device__ __forceinline__ float dppf(float v) {
    return __builtin_bit_cast(float,
        __builtin_amdgcn_update_dpp(0, __builtin_bit_cast(int, v), CTRL, 0xF, 0xF, true));
}

// 64-lane all-lanes sum: 4 DPP butterfly levels + shfl_xor 16/32.
// PROVEN form (rounds 8/11/12/13). BANNED substitutes: permlane16/32_swap
// (failed r9/r10), magic-constant rsqrt downstream (failed r14/r15).
__device__ __forceinline__ float wave_sum(float v) {
    v += dppf<0xB1>(v);    // quad_perm {1,0,3,2}  : xor1
    v += dppf<0x4E>(v);    // quad_perm {2,3,0,1}  : xor2
    v += dppf<0x124>(v);   // row_ror:4
    v += dppf<0x128>(v);   // row_ror:8  -> every lane holds its 16-lane row sum
    v += __shfl_xor(v, 16, 64);
    v += __shfl_xor(v, 32, 64);
    return v;
}

// sg = sign(d) * 2^-23 (copysign via bit-field insert)
__device__ __forceinline__ float sign_bfi(float d, unsigned smask, float smag) {
    float r;
    asm("v_bfi_b32 %0, %1, %2, %3" : "=v"(r) : "v"(smask), "v"(d), "v"(smag));
    return r;
}

__global__ __launch_bounds__(256) void adam_rows_kernel(
    const float* __restrict__ s,       // [NROWS, DDIM]
    const float* __restrict__ tconf,   // [NROWS, 1]
    const float* __restrict__ W,       // [1, DDIM]
    const float* __restrict__ bias,    // [1]
    float* __restrict__ out,           // [NROWS, DDIM]
    const StepTbl tbl)
{
    const int lane = threadIdx.x & 63;
    const int wave = threadIdx.x >> 6;
    const int row  = blockIdx.x * WPB + wave;

    const float bb = bias[0];
    const float tc = tconf[row];

    const float GZS      = 2.0f / (float)NROWS;
    const float NLOG2E   = -1.44269504f;
    const unsigned SMASK = 0x80000000u;
    const float    SMAG  = 1.1920929e-7f;   // 2^-23 == 1/(NROWS*DDIM) exactly

    const f32x2 b12    = {0.9f, 0.9f};
    const f32x2 b22    = {0.999f, 0.999f};
    const f32x2 mhalf2 = {-0.5f, -0.5f};
    const f32x2 th2    = {1.5f, 1.5f};

    // Loop state: 5 arrays x 8 pairs = 80 VGPRs.
    // y2 tracks rsqrt(V+delta): exact v_rsq reseed on steps 0,1, every 4th, 49;
    // clamped Newton update (all full-rate) on the other steps.
    f32x2 w2[NPAIR], diff2[NPAIR], M2[NPAIR], V2[NPAIR], y2[NPAIR];

    const float4* W4 = reinterpret_cast<const float4*>(W);
    const float4* S4 = reinterpret_cast<const float4*>(s + (size_t)row * DDIM);

    // Load w; fold s0 contribution into a single scalar zb = s0.w + b
    float dot0 = 0.0f;
    #pragma unroll
    for (int c = 0; c < 4; ++c) {
        float4 wv = W4[c * 64 + lane];
        float4 sv = S4[c * 64 + lane];
        w2[2*c+0] = (f32x2){wv.x, wv.y};
        w2[2*c+1] = (f32x2){wv.z, wv.w};
        dot0 = fmaf(sv.x, wv.x, dot0);
        dot0 = fmaf(sv.y, wv.y, dot0);
        dot0 = fmaf(sv.z, wv.z, dot0);
        dot0 = fmaf(sv.w, wv.w, dot0);
    }
    const float zb = wave_sum(dot0) + bb;

    float ddot = 0.0f;   // per-lane partial of diff . w

    // ---- Step 0 peeled: diff == 0 -> sign term exactly 0; exact y seed ----
    {
        const float e  = __builtin_amdgcn_exp2f(zb * NLOG2E);
        const float p  = __builtin_amdgcn_rcpf(1.0f + e);
        const float gz = GZS * (p - tc) * (p * (1.0f - p));

        const f32x2 gz2  = {gz, gz};
        const f32x2 nal2 = {-tbl.alpha[0], -tbl.alpha[0]};
        const f32x2 de2  = {tbl.delta[0], tbl.delta[0]};

        #pragma unroll
        for (int i = 0; i < NPAIR; ++i) {
            const f32x2 g = gz2 * w2[i];
            M2[i] = g;
            V2[i] = g * g;

            const f32x2 vd = V2[i] + de2;
            y2[i].x = __builtin_amdgcn_rsqf(vd.x);
            y2[i].y = __builtin_amdgcn_rsqf(vd.y);

            diff2[i] = nal2 * (M2[i] * y2[i]);

            ddot = fmaf(diff2[i].x, w2[i].x, ddot);
            ddot = fmaf(diff2[i].y, w2[i].y, ddot);
        }
    }

    // One Adam step. EXACT: y = v_rsq(V+delta). Cheap: one clamped Newton
    // update of y (V only ever grows fast, never shrinks fast -> tracking
    // errors understep; clamp bounds the transient; exact reseed <=3 steps away).
#define DO_STEP(STEP_IDX, EXACT)                                              \
    {                                                                          \
        const int step = (STEP_IDX);                                           \
        const float z  = zb + wave_sum(ddot);                                  \
        const float e  = __builtin_amdgcn_exp2f(z * NLOG2E);                   \
        const float p  = __builtin_amdgcn_rcpf(1.0f + e);                      \
        const float gz = GZS * (p - tc) * (p * (1.0f - p));                    \
        const float alpha = tbl.alpha[step];                                   \
        const float delta = tbl.delta[step];                                   \
        const f32x2 gz2  = {gz, gz};                                           \
        const f32x2 nal2 = {-alpha, -alpha};                                   \
        const f32x2 de2  = {delta, delta};                                     \
        ddot = 0.0f;                                                           \
        _Pragma("unroll")                                                      \
        for (int i = 0; i < NPAIR; ++i) {                                      \
            f32x2 sg;                                                          \
            sg.x = sign_bfi(diff2[i].x, SMASK, SMAG);                          \
            sg.y = sign_bfi(diff2[i].y, SMASK, SMAG);                          \
            const f32x2 g = __builtin_elementwise_fma(gz2, w2[i], sg);         \
            M2[i] = __builtin_elementwise_fma(b12, M2[i], g);                  \
            V2[i] = __builtin_elementwise_fma(g, g, V2[i] * b22);              \
            const f32x2 vd = V2[i] + de2;                                      \
            if (EXACT) {                                                       \
                y2[i].x = __builtin_amdgcn_rsqf(vd.x);                         \
                y2[i].y = __builtin_amdgcn_rsqf(vd.y);                         \
            } else {                                                           \
                const f32x2 t = y2[i] * y2[i];                                 \
                const f32x2 q = vd * t;                                        \
                f32x2 f = __builtin_elementwise_fma(mhalf2, q, th2);           \
                f.x = __builtin_amdgcn_fmed3f(f.x, 0.5f, 1.5f);                \
                f.y = __builtin_amdgcn_fmed3f(f.y, 0.5f, 1.5f);                \
                y2[i] = y2[i] * f;                                             \
            }                                                                  \
            diff2[i] = __builtin_elementwise_fma(nal2, M2[i] * y2[i], diff2[i]); \
            ddot = fmaf(diff2[i].x, w2[i].x, ddot);                            \
            ddot = fmaf(diff2[i].y, w2[i].y, ddot);                            \
        }                                                                      \
    }

    // ---- Steps 1..48: 12 macro-steps of {exact, cheap, cheap, cheap} ----
    for (int m = 0; m < 12; ++m) {
        const int sb = 1 + 4 * m;
        DO_STEP(sb + 0, true);
        DO_STEP(sb + 1, false);
        DO_STEP(sb + 2, false);
        DO_STEP(sb + 3, false);
    }
    // ---- Step 49: exact ----
    DO_STEP(49, true);
#undef DO_STEP

    // Epilogue: reload s0, write sp = s0 + diff
    float4* O4 = reinterpret_cast<float4*>(out + (size_t)row * DDIM);
    #pragma unroll
    for (int c = 0; c < 4; ++c) {
        float4 sv = S4[c * 64 + lane];
        float4 ov;
        ov.x = sv.x + diff2[2*c+0].x;
        ov.y = sv.y + diff2[2*c+0].y;
        ov.z = sv.z + diff2[2*c+1].x;
        ov.w = sv.w + diff2[2*c+1].y;
        O4[c * 64 + lane] = ov;
    }
}

extern "C" void kernel_launch(void* const* d_in, const int* in_sizes, int n_in,
                              void* d_out, int out_size, void* d_ws, size_t ws_size,
                              hipStream_t stream) {
    const float* s     = (const float*)d_in[0];
    const float* tconf = (const float*)d_in[1];
    const float* W     = (const float*)d_in[2];
    const float* bias  = (const float*)d_in[3];
    float* out = (float*)d_out;

    // Host-side per-step Adam constants (double precision, then narrowed).
    StepTbl tbl;
    double b1p = 1.0, b2p = 1.0;
    for (int t = 0; t < NSTEPS; ++t) {
        b1p *= B1_D;
        b2p *= B2_D;
        const double c1 = 1.0 - b1p;                 // 1 - B1^t
        const double c2 = 1.0 - b2p;                 // 1 - B2^t
        const double sc = sqrt(c2 / (1.0 - B2_D));   // sqrt((1-B2^t)/(1-B2))
        tbl.alpha[t] = (float)(LR_D * (1.0 - B1_D) * sc / c1);
        const float eps2 = (float)(EPS_D * sc);
        tbl.delta[t] = eps2 * eps2;
    }

    dim3 grid(NROWS / WPB);   // 2048 blocks, 1 row/wave
    dim3 block(64 * WPB);     // 256 threads
    adam_rows_kernel<<<grid, block, 0, stream>>>(s, tconf, W, bias, out, tbl);
}

// Round 17
// 105.203 us; speedup vs baseline: 1.0859x; 1.0859x over previous
//
#include <hip/hip_runtime.h>
#include <math.h>

// Problem constants (match reference)
#define NROWS   8192
#define DDIM    1024
#define NSTEPS  50
#define NPAIR   8           // float2 pairs per lane (16 elements)
#define WPB     4           // waves per block -> 256 threads

// Adam hyperparams (double for host-side table computation)
#define LR_D   0.01
#define B1_D   0.9
#define B2_D   0.999
#define EPS_D  1e-8

typedef __attribute__((ext_vector_type(2))) float f32x2;

struct StepTbl {
    float alpha[NSTEPS];   // LR*(1-B1)*sqrt((1-B2^t)/(1-B2))/(1-B1^t)
    float delta[NSTEPS];   // eps2^2, eps2 = EPS*sqrt((1-B2^t)/(1-B2))
};

// DPP-permuted copy of v (f32 through int bit_cast). bound_ctrl=1 (0 on invalid).
template <int CTRL>
__device__ __forceinline__ float dppf(float v) {
    return __builtin_bit_cast(float,
        __builtin_amdgcn_update_dpp(0, __builtin_bit_cast(int, v), CTRL, 0xF, 0xF, true));
}

// 64-lane all-lanes sum: 4 DPP butterfly levels + shfl_xor 16/32.
// PROVEN form (rounds 8/11/12/13/16). BANNED substitutes after repeated HW
// failures: permlane16/32_swap (r9/r10), magic-constant rsqrt (r14/r15),
// DPP row_bcast (r14, confounded but unverifiable). v_rsq replacement by
// full-rate Newton tracking REGRESSED (r16: trans cost ~5cyc, not 16).
__device__ __forceinline__ float wave_sum(float v) {
    v += dppf<0xB1>(v);    // quad_perm {1,0,3,2}  : xor1
    v += dppf<0x4E>(v);    // quad_perm {2,3,0,1}  : xor2
    v += dppf<0x124>(v);   // row_ror:4
    v += dppf<0x128>(v);   // row_ror:8  -> every lane holds its 16-lane row sum
    v += __shfl_xor(v, 16, 64);
    v += __shfl_xor(v, 32, 64);
    return v;
}

// sg = sign(d) * 2^-23 (copysign via bit-field insert)
__device__ __forceinline__ float sign_bfi(float d, unsigned smask, float smag) {
    float r;
    asm("v_bfi_b32 %0, %1, %2, %3" : "=v"(r) : "v"(smask), "v"(d), "v"(smag));
    return r;
}

__global__ __launch_bounds__(256) void adam_rows_kernel(
    const float* __restrict__ s,       // [NROWS, DDIM]
    const float* __restrict__ tconf,   // [NROWS, 1]
    const float* __restrict__ W,       // [1, DDIM]
    const float* __restrict__ bias,    // [1]
    float* __restrict__ out,           // [NROWS, DDIM]
    const StepTbl tbl)
{
    const int lane = threadIdx.x & 63;
    const int wave = threadIdx.x >> 6;
    const int row  = blockIdx.x * WPB + wave;

    const float bb = bias[0];
    const float tc = tconf[row];

    const float GZS      = 2.0f / (float)NROWS;
    const float NLOG2E   = -1.44269504f;
    const unsigned SMASK = 0x80000000u;
    const float    SMAG  = 1.1920929e-7f;   // 2^-23 == 1/(NROWS*DDIM) exactly

    const f32x2 b12  = {0.9f, 0.9f};
    const f32x2 b22  = {0.999f, 0.999f};

    // Loop state: 4 arrays x 8 pairs = 64 VGPRs
    f32x2 w2[NPAIR], diff2[NPAIR], M2[NPAIR], V2[NPAIR];

    const float4* W4 = reinterpret_cast<const float4*>(W);
    const float4* S4 = reinterpret_cast<const float4*>(s + (size_t)row * DDIM);

    // Load w; fold s0 contribution into a single scalar zb = s0.w + b
    float dot0 = 0.0f;
    #pragma unroll
    for (int c = 0; c < 4; ++c) {
        float4 wv = W4[c * 64 + lane];
        float4 sv = S4[c * 64 + lane];
        w2[2*c+0] = (f32x2){wv.x, wv.y};
        w2[2*c+1] = (f32x2){wv.z, wv.w};
        dot0 = fmaf(sv.x, wv.x, dot0);
        dot0 = fmaf(sv.y, wv.y, dot0);
        dot0 = fmaf(sv.z, wv.z, dot0);
        dot0 = fmaf(sv.w, wv.w, dot0);
    }
    const float zb = wave_sum(dot0) + bb;

    float ddot = 0.0f;   // per-lane partial of diff . w

    // ---- Step 0 peeled: diff == 0 -> sign term exactly 0, M=g, V=g^2 ----
    {
        const float e  = __builtin_amdgcn_exp2f(zb * NLOG2E);
        const float p  = __builtin_amdgcn_rcpf(1.0f + e);
        const float gz = GZS * (p - tc) * (p * (1.0f - p));

        const f32x2 gz2  = {gz, gz};
        const f32x2 nal2 = {-tbl.alpha[0], -tbl.alpha[0]};
        const f32x2 de2  = {tbl.delta[0], tbl.delta[0]};

        #pragma unroll
        for (int i = 0; i < NPAIR; ++i) {
            const f32x2 g = gz2 * w2[i];
            M2[i] = g;
            V2[i] = g * g;

            const f32x2 vd = V2[i] + de2;
            f32x2 u;
            u.x = __builtin_amdgcn_rsqf(vd.x);
            u.y = __builtin_amdgcn_rsqf(vd.y);

            diff2[i] = nal2 * (M2[i] * u);

            ddot = fmaf(diff2[i].x, w2[i].x, ddot);
            ddot = fmaf(diff2[i].y, w2[i].y, ddot);
        }
    }

    // ---- Steps 1..49 ----
    for (int step = 1; step < NSTEPS; ++step) {
        const float z  = zb + wave_sum(ddot);
        const float e  = __builtin_amdgcn_exp2f(z * NLOG2E);       // e^-z
        const float p  = __builtin_amdgcn_rcpf(1.0f + e);
        const float gz = GZS * (p - tc) * (p * (1.0f - p));

        const float alpha = tbl.alpha[step];
        const float delta = tbl.delta[step];

        const f32x2 gz2  = {gz, gz};
        const f32x2 nal2 = {-alpha, -alpha};
        const f32x2 de2  = {delta, delta};

        ddot = 0.0f;
        #pragma unroll
        for (int i = 0; i < NPAIR; ++i) {
            // sg = sign(diff)*2^-23 via v_bfi (diff==+-0 measure-zero for steps>=1)
            f32x2 sg;
            sg.x = sign_bfi(diff2[i].x, SMASK, SMAG);
            sg.y = sign_bfi(diff2[i].y, SMASK, SMAG);

            const f32x2 g = __builtin_elementwise_fma(gz2, w2[i], sg);

            M2[i] = __builtin_elementwise_fma(b12, M2[i], g);        // M = b1*M + g
            V2[i] = __builtin_elementwise_fma(g, g, V2[i] * b22);    // V = b2*V + g^2

            // u ~= 1/(sqrt(V)+eps2) approximated by rsq(V + eps2^2)
            const f32x2 vd = V2[i] + de2;
            f32x2 u;
            u.x = __builtin_amdgcn_rsqf(vd.x);
            u.y = __builtin_amdgcn_rsqf(vd.y);

            diff2[i] = __builtin_elementwise_fma(nal2, M2[i] * u, diff2[i]);

            // serial scalar accumulation (round-8 order)
            ddot = fmaf(diff2[i].x, w2[i].x, ddot);
            ddot = fmaf(diff2[i].y, w2[i].y, ddot);
        }
    }

    // Epilogue: reload s0, write sp = s0 + diff
    float4* O4 = reinterpret_cast<float4*>(out + (size_t)row * DDIM);
    #pragma unroll
    for (int c = 0; c < 4; ++c) {
        float4 sv = S4[c * 64 + lane];
        float4 ov;
        ov.x = sv.x + diff2[2*c+0].x;
        ov.y = sv.y + diff2[2*c+0].y;
        ov.z = sv.z + diff2[2*c+1].x;
        ov.w = sv.w + diff2[2*c+1].y;
        O4[c * 64 + lane] = ov;
    }
}

extern "C" void kernel_launch(void* const* d_in, const int* in_sizes, int n_in,
                              void* d_out, int out_size, void* d_ws, size_t ws_size,
                              hipStream_t stream) {
    const float* s     = (const float*)d_in[0];
    const float* tconf = (const float*)d_in[1];
    const float* W     = (const float*)d_in[2];
    const float* bias  = (const float*)d_in[3];
    float* out = (float*)d_out;

    // Host-side per-step Adam constants (double precision, then narrowed).
    StepTbl tbl;
    double b1p = 1.0, b2p = 1.0;
    for (int t = 0; t < NSTEPS; ++t) {
        b1p *= B1_D;
        b2p *= B2_D;
        const double c1 = 1.0 - b1p;                 // 1 - B1^t
        const double c2 = 1.0 - b2p;                 // 1 - B2^t
        const double sc = sqrt(c2 / (1.0 - B2_D));   // sqrt((1-B2^t)/(1-B2))
        tbl.alpha[t] = (float)(LR_D * (1.0 - B1_D) * sc / c1);
        const float eps2 = (float)(EPS_D * sc);
        tbl.delta[t] = eps2 * eps2;
    }

    dim3 grid(NROWS / WPB);   // 2048 blocks, 1 row/wave, full occupancy
    dim3 block(64 * WPB);     // 256 threads
    adam_rows_kernel<<<grid, block, 0, stream>>>(s, tconf, W, bias, out, tbl);
}